// Round 1
// baseline (648.316 us; speedup 1.0000x reference)
//
#include <hip/hip_runtime.h>
#include <math.h>

#define NBINS 15

// ---------------------------------------------------------------------------
// rank_pair: reproduces np.interp(linspace(0, N, 16), arange(N), sorted) rank
// arithmetic. Edge k interpolates between sorted[i0] and sorted[i1].
// ---------------------------------------------------------------------------
__device__ __forceinline__ void rank_pair(int k, int N, int* i0, int* i1, double* frac) {
    double p = (double)k * (double)N / 15.0;
    double fl = floor(p);
    int a = (int)fl; if (a > N - 1) a = N - 1;
    int b = a + 1;   if (b > N - 1) b = N - 1;
    *i0 = a; *i1 = b; *frac = p - fl;
}

// ---------------------------------------------------------------------------
// K1: one wave per row. Online softmax-denominator + argmax (first-occurrence
// tie-break). Writes conf[row], acc[row]; lane 0 also histograms the top 16
// bits of conf's float bit pattern (all conf in (0,1] -> positive floats, so
// uint bit order == float order).
// ---------------------------------------------------------------------------
__global__ __launch_bounds__(256) void k_rowstats(
    const float* __restrict__ logits, const int* __restrict__ labels,
    float* __restrict__ conf, float* __restrict__ acc,
    unsigned int* __restrict__ hist1, int N, int C) {
    const int wid  = threadIdx.x >> 6;
    const int lane = threadIdx.x & 63;
    const int row  = blockIdx.x * 4 + wid;
    if (row >= N) return;

    const float*  rp = logits + (size_t)row * (size_t)C;
    const float4* rv = (const float4*)rp;
    const int nvec = C >> 2;

    float m = -INFINITY;
    float s = 0.0f;
    int   mi = 0;

    for (int k = lane; k < nvec; k += 64) {
        float4 v = rv[k];
        int idx = k << 2;
        { float x = v.x; float nm = fmaxf(m, x); s = s * __expf(m - nm) + __expf(x - nm); mi = (x > m) ? idx     : mi; m = nm; }
        { float x = v.y; float nm = fmaxf(m, x); s = s * __expf(m - nm) + __expf(x - nm); mi = (x > m) ? idx + 1 : mi; m = nm; }
        { float x = v.z; float nm = fmaxf(m, x); s = s * __expf(m - nm) + __expf(x - nm); mi = (x > m) ? idx + 2 : mi; m = nm; }
        { float x = v.w; float nm = fmaxf(m, x); s = s * __expf(m - nm) + __expf(x - nm); mi = (x > m) ? idx + 3 : mi; m = nm; }
    }
    // tail (C % 4 != 0); no-op for C = 1000
    for (int idx = (nvec << 2) + lane; idx < C; idx += 64) {
        float x = rp[idx]; float nm = fmaxf(m, x);
        s = s * __expf(m - nm) + __expf(x - nm);
        mi = (x > m) ? idx : mi; m = nm;
    }

    // wave butterfly reduce: (max, first-index, rescaled sum)
    for (int off = 32; off > 0; off >>= 1) {
        float om  = __shfl_xor(m, off);
        float os  = __shfl_xor(s, off);
        int   omi = __shfl_xor(mi, off);
        float M = fmaxf(m, om);
        s = s * __expf(m - M) + os * __expf(om - M);
        if (om > m || (om == m && omi < mi)) mi = omi;
        m = M;
    }

    if (lane == 0) {
        float cv = 1.0f / s;               // max(softmax) == 1 / sum(exp(x - max))
        conf[row] = cv;
        acc[row]  = (mi == labels[row]) ? 1.0f : 0.0f;
        atomicAdd(&hist1[__float_as_uint(cv) >> 16], 1u);
    }
}

__global__ void k_zero(unsigned int* p, int n) {
    int i = blockIdx.x * blockDim.x + threadIdx.x;
    if (i < n) p[i] = 0u;
}

// ---------------------------------------------------------------------------
// K3: single block. Scan the 65536-bin top-16 histogram; for each of the 32
// target ranks record its bucket (meta[j]) and base cumulative count
// (meta[32+j]).
// ---------------------------------------------------------------------------
__global__ __launch_bounds__(1024) void k_scan1(
    const unsigned int* __restrict__ hist1, unsigned int* __restrict__ meta, int N) {
    __shared__ unsigned int tmp[1024];
    __shared__ unsigned int R[32];
    const int t = threadIdx.x;
    if (t < 32) {
        int k = t >> 1; int i0, i1; double fr;
        rank_pair(k, N, &i0, &i1, &fr);
        R[t] = (unsigned int)((t & 1) ? i1 : i0);
    }
    const int base = t * 64;
    unsigned int local = 0;
    for (int b = 0; b < 64; b++) local += hist1[base + b];
    tmp[t] = local;
    __syncthreads();
    for (int off = 1; off < 1024; off <<= 1) {
        unsigned int v = (t >= off) ? tmp[t - off] : 0u;
        __syncthreads();
        tmp[t] += v;
        __syncthreads();
    }
    unsigned int cum = tmp[t] - local;   // exclusive prefix for this thread's 64 bins
    for (int b = 0; b < 64; b++) {
        unsigned int c = hist1[base + b];
        if (c) {
            for (int j = 0; j < 32; j++) {
                unsigned int r = R[j];
                if (r >= cum && r < cum + c) {
                    meta[j]      = (unsigned int)(base + b);
                    meta[32 + j] = cum;
                }
            }
        }
        cum += c;
    }
}

// ---------------------------------------------------------------------------
// K4: low-16-bit histograms restricted to each rank's bucket (32 slots).
// ---------------------------------------------------------------------------
__global__ __launch_bounds__(256) void k_hist2(
    const float* __restrict__ conf, const unsigned int* __restrict__ meta,
    unsigned int* __restrict__ hist2, int N) {
    __shared__ unsigned int bk[32];
    if (threadIdx.x < 32) bk[threadIdx.x] = meta[threadIdx.x];
    __syncthreads();
    int i = blockIdx.x * blockDim.x + threadIdx.x;
    if (i < N) {
        unsigned int key = __float_as_uint(conf[i]);
        unsigned int top = key >> 16, low = key & 0xFFFFu;
        #pragma unroll
        for (int j = 0; j < 32; j++)
            if (bk[j] == top) atomicAdd(&hist2[((unsigned int)j << 16) + low], 1u);
    }
}

// ---------------------------------------------------------------------------
// K5: one block per rank; scan its 65536-bin low-16 histogram to find the
// exact bit pattern of sorted[rank]. Writes meta[64+j].
// ---------------------------------------------------------------------------
__global__ __launch_bounds__(1024) void k_scan2(
    const unsigned int* __restrict__ hist2, unsigned int* __restrict__ meta, int N) {
    const int j = blockIdx.x;
    const unsigned int* h = hist2 + ((unsigned int)j << 16);
    __shared__ unsigned int tmp[1024];
    const int t = threadIdx.x;

    int k = j >> 1; int i0, i1; double fr;
    rank_pair(k, N, &i0, &i1, &fr);
    unsigned int target = (unsigned int)((j & 1) ? i1 : i0) - meta[32 + j];

    const int base = t * 64;
    unsigned int local = 0;
    for (int b = 0; b < 64; b++) local += h[base + b];
    tmp[t] = local;
    __syncthreads();
    for (int off = 1; off < 1024; off <<= 1) {
        unsigned int v = (t >= off) ? tmp[t - off] : 0u;
        __syncthreads();
        tmp[t] += v;
        __syncthreads();
    }
    unsigned int cum = tmp[t] - local;
    for (int b = 0; b < 64; b++) {
        unsigned int c = h[base + b];
        if (c && target >= cum && target < cum + c)
            meta[64 + j] = (meta[j] << 16) | (unsigned int)(base + b);
        cum += c;
    }
}

// ---------------------------------------------------------------------------
// K5b: compute the 16 edges in double (matches np.interp f64 semantics);
// stored as double[16] at meta word offset 96.
// ---------------------------------------------------------------------------
__global__ void k_edges(unsigned int* meta, int N) {
    int k = threadIdx.x;
    if (k >= 16) return;
    int i0, i1; double fr;
    rank_pair(k, N, &i0, &i1, &fr);
    float s0 = __uint_as_float(meta[64 + 2 * k]);
    float s1 = __uint_as_float(meta[64 + 2 * k + 1]);
    double e = (double)s0 + fr * ((double)s1 - (double)s0);
    ((double*)(meta + 96))[k] = e;
}

// meta float-word offsets for the global bin accumulators
#define CNT_OFF  128
#define ACC_OFF  144
#define CONF_OFF 160

// ---------------------------------------------------------------------------
// K6: bin assignment (searchsorted-left on edges[1..15], clip to 14, drop
// conf <= edges[0]) + LDS-reduced accumulation into 15 global bins.
// ---------------------------------------------------------------------------
__global__ __launch_bounds__(256) void k_bin(
    const float* __restrict__ conf, const float* __restrict__ acc,
    float* __restrict__ metaf, int N) {
    __shared__ double e[16];
    __shared__ float c15[NBINS], a15[NBINS], f15[NBINS];
    const int t = threadIdx.x;
    if (t < 16) e[t] = ((const double*)(metaf + 96))[t];
    if (t < NBINS) { c15[t] = 0.f; a15[t] = 0.f; f15[t] = 0.f; }
    __syncthreads();
    int i = blockIdx.x * blockDim.x + t;
    if (i < N) {
        float cf = conf[i];
        double c = (double)cf;
        if (c > e[0]) {
            int bin = 0;
            #pragma unroll
            for (int k = 1; k < 16; k++) bin += (e[k] < c) ? 1 : 0;
            if (bin > NBINS - 1) bin = NBINS - 1;
            atomicAdd(&c15[bin], 1.0f);
            atomicAdd(&a15[bin], acc[i]);
            atomicAdd(&f15[bin], cf);
        }
    }
    __syncthreads();
    if (t < NBINS) {
        atomicAdd(&metaf[CNT_OFF + t],  c15[t]);
        atomicAdd(&metaf[ACC_OFF + t],  a15[t]);
        atomicAdd(&metaf[CONF_OFF + t], f15[t]);
    }
}

// ---------------------------------------------------------------------------
// K7: ece = sum over non-empty bins of |avg_conf - avg_acc| * count / N
// ---------------------------------------------------------------------------
__global__ void k_final(const float* __restrict__ metaf, float* __restrict__ out, int N) {
    const int t = threadIdx.x;
    float term = 0.0f;
    if (t < NBINS) {
        float cnt = metaf[CNT_OFF + t];
        float sa  = metaf[ACC_OFF + t];
        float sc  = metaf[CONF_OFF + t];
        float denom = fmaxf(cnt, 1.0f);
        if (cnt > 0.0f) term = fabsf(sc / denom - sa / denom) * (cnt / (float)N);
    }
    for (int off = 32; off > 0; off >>= 1) term += __shfl_down(term, off);
    if (t == 0) out[0] = term;
}

extern "C" void kernel_launch(void* const* d_in, const int* in_sizes, int n_in,
                              void* d_out, int out_size, void* d_ws, size_t ws_size,
                              hipStream_t stream) {
    const float* logits = (const float*)d_in[0];
    const int*   labels = (const int*)d_in[1];
    const int N = in_sizes[1];
    const int C = in_sizes[0] / N;

    // workspace layout (float/uint words):
    //   [0, N)            conf
    //   [N, 2N)           acc
    //   [2N, 2N+65536)    hist1 (top-16 histogram)
    //   next 256 words    meta: buckets[32] | bases[32] | V[32] | edges double[16] | bins 3x16
    //   next 32*65536     hist2 (per-rank low-16 histograms)
    float* ws = (float*)d_ws;
    float*        conf  = ws;
    float*        acc   = ws + (size_t)N;
    unsigned int* hist1 = (unsigned int*)(ws + 2 * (size_t)N);
    unsigned int* meta  = hist1 + 65536;
    unsigned int* hist2 = meta + 256;
    float*        metaf = (float*)meta;
    float*        out   = (float*)d_out;

    const int nz = 65536 + 256 + 32 * 65536;
    k_zero<<<(nz + 255) / 256, 256, 0, stream>>>(hist1, nz);
    k_rowstats<<<(N + 3) / 4, 256, 0, stream>>>(logits, labels, conf, acc, hist1, N, C);
    k_scan1<<<1, 1024, 0, stream>>>(hist1, meta, N);
    k_hist2<<<(N + 255) / 256, 256, 0, stream>>>(conf, meta, hist2, N);
    k_scan2<<<32, 1024, 0, stream>>>(hist2, meta, N);
    k_edges<<<1, 64, 0, stream>>>(meta, N);
    k_bin<<<(N + 255) / 256, 256, 0, stream>>>(conf, acc, metaf, N);
    k_final<<<1, 64, 0, stream>>>(metaf, out, N);
}